// Round 6
// baseline (231.065 us; speedup 1.0000x reference)
//
#include <hip/hip_runtime.h>
#include <hip/hip_cooperative_groups.h>
#include <math.h>

namespace cg = cooperative_groups;

#define CHW  (64*16384)
#define ATT_SCALE 0.17677669529663687f  // 1/sqrt(32)

__device__ __forceinline__ float poly_exp(float d) {
  // exp(d), |d| <= 0.1768 ; deg-4 Taylor, rel err ~1.4e-6; e^c factor cancels in softmax
  return 1.f + d*(1.f + d*(0.5f + d*(0.16666667f + d*0.04166667f)));
}

// One cooperative kernel, 256 blocks x 512 threads, 3 grid syncs.
// P1: a = (w1b@w1a)@x + b, stats partials; block 0 folds wc@w2 -> wfold.
// P2: grid attention (keys built from `a` in LDS; pad-token compression).
// P3: y = x + Wf@att + b -> out;  h1 = relu(wf1@y) -> ws.
// P4: out = y + wf3@relu(dilconv(h1)+bf2) + bf3  (one row per block).
__global__ __launch_bounds__(512) void mega(
    const float* __restrict__ x, const float* __restrict__ w1a,
    const float* __restrict__ b1a, const float* __restrict__ w1b,
    const float* __restrict__ b1b, const float* __restrict__ wqk,
    const float* __restrict__ w2p, const float* __restrict__ b2p,
    const float* __restrict__ wcp, const float* __restrict__ bcp,
    const float* __restrict__ wf1, const float* __restrict__ bf1,
    const float* __restrict__ wf2, const float* __restrict__ bf2,
    const float* __restrict__ wf3, const float* __restrict__ bf3,
    float* __restrict__ a, float* __restrict__ statsbuf,
    float* __restrict__ att, float* __restrict__ h1,
    float* __restrict__ wfold, float* out) {
  __shared__ __align__(16) char smraw[48448];
  cg::grid_group gg = cg::this_grid();
  int tid = threadIdx.x;
  int bi = blockIdx.x;

  // ================= P1: a + stats =================
  {
    float* sA  = (float*)smraw;              // [256]
    float* pc  = (float*)(smraw + 1024);     // [4][4][512]
    float* rs  = (float*)(smraw + 33792);    // [128]
    float* rq  = (float*)(smraw + 34304);    // [128]
    float* sb1 = (float*)(smraw + 34816);    // [4]
    if (tid < 256) {
      int o = tid >> 6, c = tid & 63;
      float s = 0.f;
      #pragma unroll
      for (int k = 0; k < 4; ++k) s += w1b[o*4+k] * w1a[k*64+c];
      sA[tid] = s;
    }
    if (tid < 4) {
      float s = b1b[tid];
      #pragma unroll
      for (int k = 0; k < 4; ++k) s += w1b[tid*4+k] * b1a[k];
      sb1[tid] = s;
    }
    __syncthreads();
    int quad = tid & 31, cgi = tid >> 5;        // 32 quads x 16 channel-groups
    int gq = bi*32 + quad;
    int bb = gq >> 12, px0 = (gq & 4095) * 4;
    const float* xp = x + bb*CHW + (cgi*4)*16384 + px0;
    float4 acc[4];
    #pragma unroll
    for (int o = 0; o < 4; ++o) acc[o] = make_float4(0.f,0.f,0.f,0.f);
    #pragma unroll
    for (int cc = 0; cc < 4; ++cc) {
      float4 xv = *(const float4*)(xp + cc*16384);
      int c = cgi*4 + cc;
      #pragma unroll
      for (int o = 0; o < 4; ++o) {
        float w = sA[o*64+c];
        acc[o].x += w*xv.x; acc[o].y += w*xv.y; acc[o].z += w*xv.z; acc[o].w += w*xv.w;
      }
    }
    #pragma unroll
    for (int o = 0; o < 4; ++o) {
      pc[((0*4+o)<<9) + tid] = acc[o].x;
      pc[((1*4+o)<<9) + tid] = acc[o].y;
      pc[((2*4+o)<<9) + tid] = acc[o].z;
      pc[((3*4+o)<<9) + tid] = acc[o].w;
    }
    __syncthreads();
    if (tid < 128) {
      int q2 = tid & 31, o = tid >> 5;
      float sx=0.f, sy=0.f, sz=0.f, sw=0.f;
      #pragma unroll
      for (int g2 = 0; g2 < 16; ++g2) {
        int idx = g2*32 + q2;
        sx += pc[((0*4+o)<<9) + idx];
        sy += pc[((1*4+o)<<9) + idx];
        sz += pc[((2*4+o)<<9) + idx];
        sw += pc[((3*4+o)<<9) + idx];
      }
      float bv = sb1[o];
      sx += bv; sy += bv; sz += bv; sw += bv;
      int gq2 = bi*32 + q2;
      int b2 = gq2 >> 12, p0 = (gq2 & 4095)*4;
      *(float4*)(a + b2*65536 + o*16384 + p0) = make_float4(sx,sy,sz,sw);
      rs[tid] = sx+sy+sz+sw;
      rq[tid] = sx*sx+sy*sy+sz*sz+sw*sw;
    }
    __syncthreads();
    if (tid < 64) {
      float s1 = rs[tid] + rs[tid+64];
      float s2 = rq[tid] + rq[tid+64];
      #pragma unroll
      for (int m = 1; m < 64; m <<= 1) {
        s1 += __shfl_xor(s1, m);
        s2 += __shfl_xor(s2, m);
      }
      if (tid == 0) { statsbuf[bi*2] = s1; statsbuf[bi*2+1] = s2; }
    }
    if (bi == 0) {   // fold wc@w2 + bias once
      if (tid < 256) {
        int o = tid >> 2, k = tid & 3;
        float s = 0.f;
        for (int c = 0; c < 64; ++c) s += wcp[o*64+c] * w2p[c*4+k];
        wfold[tid] = s;
      } else if (tid < 320) {
        int o = tid - 256;
        float s = bcp[o];
        for (int c = 0; c < 64; ++c) s += wcp[o*64+c] * b2p[c];
        wfold[256+o] = s;
      }
    }
  }
  gg.sync();

  // ================= P2: attention =================
  {
    float4* kq = (float4*)smraw;             // [1024]
    float4* kt = (float4*)(smraw + 16384);   // [1024]
    float*  red = (float*)(smraw + 32768);   // [8][5][64]
    float*  padr = (float*)(smraw + 43008);  // [8][5]
    float*  swqk = (float*)(smraw + 43168);  // [16]
    float*  padout = (float*)(smraw + 43232);// [4]
    float*  smu = (float*)(smraw + 43248);   // [2]
    if (tid < 64) {
      float s1 = 0.f, s2 = 0.f;
      #pragma unroll
      for (int r = 0; r < 4; ++r) {
        s1 += statsbuf[2*(tid*4+r)];
        s2 += statsbuf[2*(tid*4+r)+1];
      }
      #pragma unroll
      for (int m = 1; m < 64; m <<= 1) {
        s1 += __shfl_xor(s1, m);
        s2 += __shfl_xor(s2, m);
      }
      if (tid == 0) { smu[0] = s1; smu[1] = s2; }
    }
    if (tid < 16) swqk[tid] = wqk[tid];
    __syncthreads();
    float mu  = smu[0] * (1.f/98304.f);
    float var = smu[1] * (1.f/98304.f) - mu*mu;
    float rsig = rsqrtf(var + 1e-5f);
    int g = bi >> 3, qb = bi & 7;
    int b = g >> 4, u = (g >> 2) & 3, v = g & 3;
    const float* abase = a + ((b*4+u) << 14);
    for (int km = tid; km < 1024; km += 512) {
      int tt = 512 + km;
      int i = tt >> 5, j = tt & 31;
      int row = (i - 16)*4 + v;
      float4 tv = *(const float4*)(abase + row*128 + (j << 2));
      tv.x = (tv.x-mu)*rsig; tv.y = (tv.y-mu)*rsig;
      tv.z = (tv.z-mu)*rsig; tv.w = (tv.w-mu)*rsig;
      float q0 = tv.x*swqk[0] + tv.y*swqk[4] + tv.z*swqk[8]  + tv.w*swqk[12];
      float q1 = tv.x*swqk[1] + tv.y*swqk[5] + tv.z*swqk[9]  + tv.w*swqk[13];
      float q2 = tv.x*swqk[2] + tv.y*swqk[6] + tv.z*swqk[10] + tv.w*swqk[14];
      float q3 = tv.x*swqk[3] + tv.y*swqk[7] + tv.z*swqk[11] + tv.w*swqk[15];
      float nrm = sqrtf(q0*q0 + q1*q1 + q2*q2 + q3*q3);
      float inv = 1.f / (nrm + 1e-8f);
      kt[km] = tv;
      kq[km] = make_float4(q0*inv, q1*inv, q2*inv, q3*inv);
    }
    float tpad = -mu * rsig;
    float c0 = swqk[0]+swqk[4]+swqk[8]+swqk[12];
    float c1 = swqk[1]+swqk[5]+swqk[9]+swqk[13];
    float c2 = swqk[2]+swqk[6]+swqk[10]+swqk[14];
    float c3 = swqk[3]+swqk[7]+swqk[11]+swqk[15];
    float p0 = tpad*c0, p1 = tpad*c1, p2 = tpad*c2, p3 = tpad*c3;
    float pn = sqrtf(p0*p0+p1*p1+p2*p2+p3*p3);
    float pinv = 1.f / (pn + 1e-8f);
    float4 qpu = make_float4(p0*pinv, p1*pinv, p2*pinv, p3*pinv);
    __syncthreads();
    int s = tid >> 5, qi = tid & 31;
    float4 q[2];
    #pragma unroll
    for (int j = 0; j < 2; ++j) {
      float4 vq = kq[qb*64 + j*32 + qi];
      q[j] = make_float4(vq.x*ATT_SCALE, vq.y*ATT_SCALE, vq.z*ATT_SCALE, vq.w*ATT_SCALE);
    }
    float den[2] = {0.f, 0.f};
    float4 ov[2];
    ov[0] = make_float4(0.f,0.f,0.f,0.f); ov[1] = make_float4(0.f,0.f,0.f,0.f);
    if (s == 0) {
      #pragma unroll
      for (int j = 0; j < 2; ++j) {
        float d = q[j].x*qpu.x + q[j].y*qpu.y + q[j].z*qpu.z + q[j].w*qpu.w;
        float e = 512.f * poly_exp(d);
        den[j] += e;
        ov[j].x += e*tpad; ov[j].y += e*tpad; ov[j].z += e*tpad; ov[j].w += e*tpad;
      }
    }
    int m0 = s * 64;
    #pragma unroll 2
    for (int m = m0; m < m0 + 64; ++m) {
      float4 kk = kq[m];
      float4 tv = kt[m];
      #pragma unroll
      for (int j = 0; j < 2; ++j) {
        float d = q[j].x*kk.x + q[j].y*kk.y + q[j].z*kk.z + q[j].w*kk.w;
        float e = poly_exp(d);
        den[j] += e;
        ov[j].x += e*tv.x; ov[j].y += e*tv.y; ov[j].z += e*tv.z; ov[j].w += e*tv.w;
      }
    }
    #pragma unroll
    for (int j = 0; j < 2; ++j) {
      den[j]  += __shfl_xor(den[j], 32);
      ov[j].x += __shfl_xor(ov[j].x, 32);
      ov[j].y += __shfl_xor(ov[j].y, 32);
      ov[j].z += __shfl_xor(ov[j].z, 32);
      ov[j].w += __shfl_xor(ov[j].w, 32);
    }
    if ((tid & 32) == 0) {
      int hs = s >> 1;
      #pragma unroll
      for (int j = 0; j < 2; ++j) {
        int slot = j*32 + qi;
        red[(hs*5+0)*64+slot] = den[j];
        red[(hs*5+1)*64+slot] = ov[j].x; red[(hs*5+2)*64+slot] = ov[j].y;
        red[(hs*5+3)*64+slot] = ov[j].z; red[(hs*5+4)*64+slot] = ov[j].w;
      }
    }
    {
      float4 qs = make_float4(qpu.x*ATT_SCALE, qpu.y*ATT_SCALE, qpu.z*ATT_SCALE, qpu.w*ATT_SCALE);
      float pd = 0.f, px = 0.f, py = 0.f, pz = 0.f, pw = 0.f;
      #pragma unroll
      for (int mm = 0; mm < 2; ++mm) {
        int m = tid + mm*512;
        float4 kk = kq[m]; float4 tv = kt[m];
        float d = qs.x*kk.x + qs.y*kk.y + qs.z*kk.z + qs.w*kk.w;
        float e = poly_exp(d);
        pd += e; px += e*tv.x; py += e*tv.y; pz += e*tv.z; pw += e*tv.w;
      }
      if (tid == 0) {
        float d = qs.x*qpu.x + qs.y*qpu.y + qs.z*qpu.z + qs.w*qpu.w;
        float e = 512.f * poly_exp(d);
        pd += e; px += e*tpad; py += e*tpad; pz += e*tpad; pw += e*tpad;
      }
      #pragma unroll
      for (int mask = 1; mask < 64; mask <<= 1) {
        pd += __shfl_xor(pd, mask);
        px += __shfl_xor(px, mask); py += __shfl_xor(py, mask);
        pz += __shfl_xor(pz, mask); pw += __shfl_xor(pw, mask);
      }
      if ((tid & 63) == 0) {
        int wv = tid >> 6;
        padr[wv*5+0] = pd; padr[wv*5+1] = px; padr[wv*5+2] = py;
        padr[wv*5+3] = pz; padr[wv*5+4] = pw;
      }
    }
    __syncthreads();
    if (tid < 64) {
      float dsum=0.f, ox=0.f, oy=0.f, oz=0.f, ow=0.f;
      #pragma unroll
      for (int ss = 0; ss < 8; ++ss) {
        dsum += red[(ss*5+0)*64+tid];
        ox += red[(ss*5+1)*64+tid]; oy += red[(ss*5+2)*64+tid];
        oz += red[(ss*5+3)*64+tid]; ow += red[(ss*5+4)*64+tid];
      }
      float inv = 1.f / dsum;
      int t = 512 + qb*64 + tid;
      int i = t >> 5, j = t & 31;
      float* ap = att + b*65536 + (i*4+u)*128 + (j*4+v);
      ap[0]     = ox*inv;
      ap[16384] = oy*inv;
      ap[32768] = oz*inv;
      ap[49152] = ow*inv;
    } else if (tid == 64) {
      float dsum=0.f, ox=0.f, oy=0.f, oz=0.f, ow=0.f;
      #pragma unroll
      for (int wv = 0; wv < 8; ++wv) {
        dsum += padr[wv*5+0];
        ox += padr[wv*5+1]; oy += padr[wv*5+2]; oz += padr[wv*5+3]; ow += padr[wv*5+4];
      }
      float inv = 1.f / dsum;
      padout[0] = ox*inv; padout[1] = oy*inv; padout[2] = oz*inv; padout[3] = ow*inv;
    }
    __syncthreads();
    if (qb == 0) {
      int i = tid >> 5, j = tid & 31;
      float* ap = att + b*65536 + (i*4+u)*128 + (j*4+v);
      ap[0] = padout[0]; ap[16384] = padout[1];
      ap[32768] = padout[2]; ap[49152] = padout[3];
    }
  }
  gg.sync();

  // ================= P3: y + h1 =================
  {
    float4* sWf4 = (float4*)smraw;           // [64]
    float*  sbfc = (float*)(smraw + 1024);   // [64]
    float*  sw1t = (float*)(smraw + 1280);   // [64][16] transposed wf1
    float*  sb1  = (float*)(smraw + 5376);   // [16]
    float4* satt = (float4*)(smraw + 5440);  // [4][32]
    float4* ylds = (float4*)(smraw + 7488);  // [64][32]
    if (tid < 64) sWf4[tid] = ((const float4*)wfold)[tid];
    else if (tid < 128) sbfc[tid-64] = wfold[256 + tid - 64];
    for (int i = tid; i < 1024; i += 512) sw1t[i] = wf1[(i & 15)*64 + (i >> 4)];
    if (tid < 16) sb1[tid] = bf1[tid];
    int quad = tid & 31, og = tid >> 5;      // 32 quads x 16 groups
    int gq = bi*32 + quad;
    int bb = gq >> 12, px0 = (gq & 4095)*4;
    if (tid < 128) {
      int k = tid >> 5, q2 = tid & 31;
      int gq2 = bi*32 + q2;
      int b2i = gq2 >> 12, p0 = (gq2 & 4095)*4;
      satt[k*32+q2] = *(const float4*)(att + b2i*65536 + k*16384 + p0);
    }
    __syncthreads();
    float4 a0 = satt[0*32+quad], a1 = satt[1*32+quad],
           a2 = satt[2*32+quad], a3 = satt[3*32+quad];
    const float* xp = x + bb*CHW + px0;
    float* yp = out + bb*CHW + px0;
    #pragma unroll
    for (int cc = 0; cc < 4; ++cc) {
      int c = og*4 + cc;
      float4 xv = *(const float4*)(xp + c*16384);
      float4 wf = sWf4[c];
      float bv = sbfc[c];
      float4 yv;
      yv.x = xv.x + wf.x*a0.x + wf.y*a1.x + wf.z*a2.x + wf.w*a3.x + bv;
      yv.y = xv.y + wf.x*a0.y + wf.y*a1.y + wf.z*a2.y + wf.w*a3.y + bv;
      yv.z = xv.z + wf.x*a0.z + wf.y*a1.z + wf.z*a2.z + wf.w*a3.z + bv;
      yv.w = xv.w + wf.x*a0.w + wf.y*a1.w + wf.z*a2.w + wf.w*a3.w + bv;
      *(float4*)(yp + c*16384) = yv;
      ylds[c*32+quad] = yv;
    }
    __syncthreads();
    float bv = sb1[og];
    float4 acc = make_float4(bv, bv, bv, bv);
    #pragma unroll 8
    for (int c = 0; c < 64; ++c) {
      float w = sw1t[c*16 + og];
      float4 yv = ylds[c*32+quad];
      acc.x += w*yv.x; acc.y += w*yv.y; acc.z += w*yv.z; acc.w += w*yv.w;
    }
    acc.x = fmaxf(acc.x,0.f); acc.y = fmaxf(acc.y,0.f);
    acc.z = fmaxf(acc.z,0.f); acc.w = fmaxf(acc.w,0.f);
    *(float4*)(h1 + bb*262144 + og*16384 + px0) = acc;
  }
  gg.sync();

  // ================= P4: dilated conv + epilogue =================
  {
    float* sbuf = (float*)smraw;             // [16][3][136]
    float* sW2t = (float*)(smraw + 26112);   // [16][3][3][16]
    float* sw3  = (float*)(smraw + 35328);   // [64][16]
    float* sb2  = (float*)(smraw + 39424);   // [16]
    float* sb3  = (float*)(smraw + 39488);   // [64]
    float* sh2  = (float*)(smraw + 39744);   // [128][17]
    int bb = bi >> 7, h = bi & 127;
    for (int idx = tid; idx < 6528; idx += 512) {
      int c = idx / 408;
      int rem = idx - c*408;
      int r = rem / 136, cl = rem - r*136;
      int row = h - 5 + 2*r;
      int gw = cl - 4;
      float v = 0.f;
      if (row >= 0 && gw >= 0 && gw < 128)
        v = h1[bb*262144 + c*16384 + row*128 + gw];
      sbuf[(c*3+r)*136 + cl] = v;
    }
    for (int i2 = tid; i2 < 2304; i2 += 512) {
      int o2 = i2 & 15, rest = i2 >> 4;
      int t = rest % 3, r = (rest/3) % 3, c = rest/9;
      sW2t[i2] = wf2[((o2*16 + c)*3 + r)*3 + t];
    }
    for (int i2 = tid; i2 < 1024; i2 += 512) sw3[i2] = wf3[i2];
    if (tid < 16) sb2[tid] = bf2[tid];
    else if (tid < 80) sb3[tid-16] = bf3[tid-16];
    __syncthreads();
    int w = tid & 127, og = tid >> 7;        // 128 px x 4 groups (4 o2 each)
    float h2[4];
    #pragma unroll
    for (int o = 0; o < 4; ++o) h2[o] = sb2[og*4+o];
    for (int c = 0; c < 16; ++c) {
      #pragma unroll
      for (int r = 0; r < 3; ++r) {
        const float* sb = &sbuf[(c*3+r)*136];
        float tm = sb[w+2];
        float t0 = sb[w+4];
        float tp = sb[w+6];
        int base = ((c*3 + r)*3) << 4;
        float4 w0 = *(const float4*)&sW2t[base + og*4];
        float4 w1 = *(const float4*)&sW2t[base + 16 + og*4];
        float4 w2v = *(const float4*)&sW2t[base + 32 + og*4];
        h2[0] += w0.x*tm + w1.x*t0 + w2v.x*tp;
        h2[1] += w0.y*tm + w1.y*t0 + w2v.y*tp;
        h2[2] += w0.z*tm + w1.z*t0 + w2v.z*tp;
        h2[3] += w0.w*tm + w1.w*t0 + w2v.w*tp;
      }
    }
    #pragma unroll
    for (int o = 0; o < 4; ++o) sh2[w*17 + og*4+o] = fmaxf(h2[o], 0.f);
    __syncthreads();
    float hv[16];
    #pragma unroll
    for (int k = 0; k < 16; ++k) hv[k] = sh2[w*17 + k];
    float* ybase = out + bb*CHW + h*128 + w;
    #pragma unroll 4
    for (int oc = 0; oc < 16; ++oc) {
      int o = og*16 + oc;
      float sv = sb3[o] + ybase[o*16384];
      const float4* s3 = (const float4*)&sw3[o*16];
      float4 s30 = s3[0], s31 = s3[1], s32 = s3[2], s33 = s3[3];
      sv += s30.x*hv[0] + s30.y*hv[1] + s30.z*hv[2] + s30.w*hv[3];
      sv += s31.x*hv[4] + s31.y*hv[5] + s31.z*hv[6] + s31.w*hv[7];
      sv += s32.x*hv[8] + s32.y*hv[9] + s32.z*hv[10] + s32.w*hv[11];
      sv += s33.x*hv[12] + s33.y*hv[13] + s33.z*hv[14] + s33.w*hv[15];
      ybase[o*16384] = sv;
    }
  }
}

extern "C" void kernel_launch(void* const* d_in, const int* in_sizes, int n_in,
                              void* d_out, int out_size, void* d_ws, size_t ws_size,
                              hipStream_t stream) {
  (void)in_sizes; (void)n_in; (void)out_size; (void)ws_size;
  const float* x   = (const float*)d_in[0];
  const float* w1a = (const float*)d_in[1];
  const float* b1a = (const float*)d_in[2];
  const float* w1b = (const float*)d_in[3];
  const float* b1b = (const float*)d_in[4];
  const float* wqk = (const float*)d_in[5];
  const float* w2  = (const float*)d_in[6];
  const float* b2  = (const float*)d_in[7];
  const float* wc  = (const float*)d_in[8];
  const float* bc  = (const float*)d_in[9];
  const float* wf1 = (const float*)d_in[10];
  const float* bf1 = (const float*)d_in[11];
  const float* wf2 = (const float*)d_in[12];
  const float* bf2 = (const float*)d_in[13];
  const float* wf3 = (const float*)d_in[14];
  const float* bf3 = (const float*)d_in[15];

  float* ws = (float*)d_ws;
  float* a_    = ws;               // 131072 floats
  float* stats = ws + 131072;      // 512
  float* att   = ws + 132096;      // 131072
  float* h1    = ws + 263168;      // 524288
  float* wfold = ws + 787456;      // 320
  float* out   = (float*)d_out;

  void* args[] = {
    (void*)&x, (void*)&w1a, (void*)&b1a, (void*)&w1b, (void*)&b1b, (void*)&wqk,
    (void*)&w2, (void*)&b2, (void*)&wc, (void*)&bc,
    (void*)&wf1, (void*)&bf1, (void*)&wf2, (void*)&bf2, (void*)&wf3, (void*)&bf3,
    (void*)&a_, (void*)&stats, (void*)&att, (void*)&h1, (void*)&wfold, (void*)&out
  };
  hipLaunchCooperativeKernel((const void*)mega, dim3(256), dim3(512), args, 0, stream);
}

// Round 7
// 135.891 us; speedup vs baseline: 1.7004x; 1.7004x over previous
//
#include <hip/hip_runtime.h>
#include <math.h>

#define CHW  (64*16384)
#define ATT_SCALE 0.17677669529663687f  // 1/sqrt(32)

__device__ __forceinline__ float poly_exp(float d) {
  // exp(d), |d| <= 0.1768 ; deg-4 Taylor, rel err ~1.4e-6; e^c factor cancels in softmax
  return 1.f + d*(1.f + d*(0.5f + d*(0.16666667f + d*0.04166667f)));
}

// ================= K1: a = (w1b@w1a)@x + b, stats partials; block0 folds wc@w2 =======
// 512 blocks x 256 threads: block = 16 pixel-quads x 16 channel-groups (4 ch each).
__global__ __launch_bounds__(256) void k1_a_stats(
    const float* __restrict__ x, const float* __restrict__ w1a,
    const float* __restrict__ b1a, const float* __restrict__ w1b,
    const float* __restrict__ b1b,
    const float* __restrict__ w2p, const float* __restrict__ b2p,
    const float* __restrict__ wcp, const float* __restrict__ bcp,
    float* __restrict__ a, float* __restrict__ statsbuf,
    float* __restrict__ wfold) {
  __shared__ float sA[256];
  __shared__ float sb1[4];
  __shared__ float pc[4][4][256];
  __shared__ float rs[64], rq[64];
  int tid = threadIdx.x;
  {
    int o = tid >> 6, c = tid & 63;
    float s = 0.f;
    #pragma unroll
    for (int k = 0; k < 4; ++k) s += w1b[o*4+k] * w1a[k*64+c];
    sA[tid] = s;
  }
  if (tid < 4) {
    float s = b1b[tid];
    #pragma unroll
    for (int k = 0; k < 4; ++k) s += w1b[tid*4+k] * b1a[k];
    sb1[tid] = s;
  }
  if (blockIdx.x == 0) {    // fold wc@w2 (+bias) once for k4
    {
      int o = tid >> 2, k = tid & 3;
      float s = 0.f;
      for (int c = 0; c < 64; ++c) s += wcp[o*64+c] * w2p[c*4+k];
      wfold[tid] = s;
    }
    if (tid < 64) {
      float s = bcp[tid];
      for (int c = 0; c < 64; ++c) s += wcp[tid*64+c] * b2p[c];
      wfold[256+tid] = s;
    }
  }
  __syncthreads();
  int quad = tid & 15, cg = tid >> 4;
  int gq = blockIdx.x * 16 + quad;
  int bb = gq >> 12;
  int px0 = (gq & 4095) * 4;
  const float* xp = x + bb*CHW + (cg*4)*16384 + px0;
  float4 acc[4];
  #pragma unroll
  for (int o = 0; o < 4; ++o) acc[o] = make_float4(0.f,0.f,0.f,0.f);
  #pragma unroll
  for (int cc = 0; cc < 4; ++cc) {
    float4 xv = *(const float4*)(xp + cc*16384);
    int c = cg*4 + cc;
    #pragma unroll
    for (int o = 0; o < 4; ++o) {
      float w = sA[o*64+c];
      acc[o].x += w*xv.x; acc[o].y += w*xv.y; acc[o].z += w*xv.z; acc[o].w += w*xv.w;
    }
  }
  #pragma unroll
  for (int o = 0; o < 4; ++o) {
    pc[0][o][tid] = acc[o].x; pc[1][o][tid] = acc[o].y;
    pc[2][o][tid] = acc[o].z; pc[3][o][tid] = acc[o].w;
  }
  __syncthreads();
  if (tid < 64) {
    int q2 = tid & 15, o = tid >> 4;
    float sx=0.f, sy=0.f, sz=0.f, sw=0.f;
    #pragma unroll
    for (int g2 = 0; g2 < 16; ++g2) {
      int idx = g2*16 + q2;
      sx += pc[0][o][idx]; sy += pc[1][o][idx];
      sz += pc[2][o][idx]; sw += pc[3][o][idx];
    }
    float bv = sb1[o];
    sx += bv; sy += bv; sz += bv; sw += bv;
    int gq2 = blockIdx.x*16 + q2;
    int b2 = gq2 >> 12; int p0 = (gq2 & 4095)*4;
    *(float4*)(a + b2*4*16384 + o*16384 + p0) = make_float4(sx,sy,sz,sw);
    rs[tid] = sx+sy+sz+sw;
    rq[tid] = sx*sx+sy*sy+sz*sz+sw*sw;
  }
  __syncthreads();
  if (tid < 64) {
    float s1 = rs[tid], s2 = rq[tid];
    #pragma unroll
    for (int m = 1; m < 64; m <<= 1) {
      s1 += __shfl_xor(s1, m);
      s2 += __shfl_xor(s2, m);
    }
    if (tid == 0) { statsbuf[blockIdx.x*2] = s1; statsbuf[blockIdx.x*2+1] = s2; }
  }
}

// ================= K23: fused tok/qk build + attention =================
// 256 blocks (32 g x 8 qb) x 512 threads. Keys built from `a` straight into LDS.
__global__ __launch_bounds__(512) void k23_attn(
    const float* __restrict__ a, const float* __restrict__ statsbuf,
    const float* __restrict__ wqk, float* __restrict__ att) {
  __shared__ float4 kq[1024];
  __shared__ float4 kt[1024];
  __shared__ float red[8][5][64];
  __shared__ float padr[8][5];
  __shared__ float swqk[16];
  __shared__ float padout[4];
  __shared__ float smu[2];
  int tid = threadIdx.x;
  if (tid < 64) {          // one wave: butterfly stats reduce
    float s1 = 0.f, s2 = 0.f;
    #pragma unroll
    for (int r = 0; r < 8; ++r) {
      s1 += statsbuf[2*(tid*8+r)];
      s2 += statsbuf[2*(tid*8+r)+1];
    }
    #pragma unroll
    for (int m = 1; m < 64; m <<= 1) {
      s1 += __shfl_xor(s1, m);
      s2 += __shfl_xor(s2, m);
    }
    if (tid == 0) { smu[0] = s1; smu[1] = s2; }
  }
  if (tid < 16) swqk[tid] = wqk[tid];
  __syncthreads();
  float mu  = smu[0] * (1.f/98304.f);
  float var = smu[1] * (1.f/98304.f) - mu*mu;
  float rsig = rsqrtf(var + 1e-5f);
  int g = blockIdx.x >> 3, qb = blockIdx.x & 7;
  int b = g >> 4, u = (g >> 2) & 3, v = g & 3;
  const float* abase = a + ((b*4+u) << 14);
  for (int km = tid; km < 1024; km += 512) {
    int tt = 512 + km;
    int i = tt >> 5, j = tt & 31;
    int row = (i - 16)*4 + v;
    float4 tv = *(const float4*)(abase + row*128 + (j << 2));
    tv.x = (tv.x-mu)*rsig; tv.y = (tv.y-mu)*rsig;
    tv.z = (tv.z-mu)*rsig; tv.w = (tv.w-mu)*rsig;
    float q0 = tv.x*swqk[0] + tv.y*swqk[4] + tv.z*swqk[8]  + tv.w*swqk[12];
    float q1 = tv.x*swqk[1] + tv.y*swqk[5] + tv.z*swqk[9]  + tv.w*swqk[13];
    float q2 = tv.x*swqk[2] + tv.y*swqk[6] + tv.z*swqk[10] + tv.w*swqk[14];
    float q3 = tv.x*swqk[3] + tv.y*swqk[7] + tv.z*swqk[11] + tv.w*swqk[15];
    float nrm = sqrtf(q0*q0 + q1*q1 + q2*q2 + q3*q3);
    float inv = 1.f / (nrm + 1e-8f);
    kt[km] = tv;
    kq[km] = make_float4(q0*inv, q1*inv, q2*inv, q3*inv);
  }
  float tpad = -mu * rsig;
  float c0 = swqk[0]+swqk[4]+swqk[8]+swqk[12];
  float c1 = swqk[1]+swqk[5]+swqk[9]+swqk[13];
  float c2 = swqk[2]+swqk[6]+swqk[10]+swqk[14];
  float c3 = swqk[3]+swqk[7]+swqk[11]+swqk[15];
  float p0 = tpad*c0, p1 = tpad*c1, p2 = tpad*c2, p3 = tpad*c3;
  float pn = sqrtf(p0*p0+p1*p1+p2*p2+p3*p3);
  float pinv = 1.f / (pn + 1e-8f);
  float4 qpu = make_float4(p0*pinv, p1*pinv, p2*pinv, p3*pinv);
  __syncthreads();
  int s = tid >> 5, qi = tid & 31;
  float4 q[2];
  #pragma unroll
  for (int j = 0; j < 2; ++j) {
    float4 vq = kq[qb*64 + j*32 + qi];
    q[j] = make_float4(vq.x*ATT_SCALE, vq.y*ATT_SCALE, vq.z*ATT_SCALE, vq.w*ATT_SCALE);
  }
  float den[2] = {0.f, 0.f};
  float4 ov[2];
  ov[0] = make_float4(0.f,0.f,0.f,0.f); ov[1] = make_float4(0.f,0.f,0.f,0.f);
  if (s == 0) {
    #pragma unroll
    for (int j = 0; j < 2; ++j) {
      float d = q[j].x*qpu.x + q[j].y*qpu.y + q[j].z*qpu.z + q[j].w*qpu.w;
      float e = 512.f * poly_exp(d);
      den[j] += e;
      ov[j].x += e*tpad; ov[j].y += e*tpad; ov[j].z += e*tpad; ov[j].w += e*tpad;
    }
  }
  int m0 = s * 64;
  #pragma unroll 2
  for (int m = m0; m < m0 + 64; ++m) {
    float4 kk = kq[m];
    float4 tv = kt[m];
    #pragma unroll
    for (int j = 0; j < 2; ++j) {
      float d = q[j].x*kk.x + q[j].y*kk.y + q[j].z*kk.z + q[j].w*kk.w;
      float e = poly_exp(d);
      den[j] += e;
      ov[j].x += e*tv.x; ov[j].y += e*tv.y; ov[j].z += e*tv.z; ov[j].w += e*tv.w;
    }
  }
  #pragma unroll
  for (int j = 0; j < 2; ++j) {
    den[j]  += __shfl_xor(den[j], 32);
    ov[j].x += __shfl_xor(ov[j].x, 32);
    ov[j].y += __shfl_xor(ov[j].y, 32);
    ov[j].z += __shfl_xor(ov[j].z, 32);
    ov[j].w += __shfl_xor(ov[j].w, 32);
  }
  if ((tid & 32) == 0) {
    int hs = s >> 1;
    #pragma unroll
    for (int j = 0; j < 2; ++j) {
      int slot = j*32 + qi;
      red[hs][0][slot] = den[j];
      red[hs][1][slot] = ov[j].x; red[hs][2][slot] = ov[j].y;
      red[hs][3][slot] = ov[j].z; red[hs][4][slot] = ov[j].w;
    }
  }
  if (qb == 0) {  // pad-query pass only where its result is used
    float4 qs = make_float4(qpu.x*ATT_SCALE, qpu.y*ATT_SCALE, qpu.z*ATT_SCALE, qpu.w*ATT_SCALE);
    float pd = 0.f, px = 0.f, py = 0.f, pz = 0.f, pw = 0.f;
    #pragma unroll
    for (int mm = 0; mm < 2; ++mm) {
      int m = tid + mm*512;
      float4 kk = kq[m]; float4 tv = kt[m];
      float d = qs.x*kk.x + qs.y*kk.y + qs.z*kk.z + qs.w*kk.w;
      float e = poly_exp(d);
      pd += e; px += e*tv.x; py += e*tv.y; pz += e*tv.z; pw += e*tv.w;
    }
    if (tid == 0) {
      float d = qs.x*qpu.x + qs.y*qpu.y + qs.z*qpu.z + qs.w*qpu.w;
      float e = 512.f * poly_exp(d);
      pd += e; px += e*tpad; py += e*tpad; pz += e*tpad; pw += e*tpad;
    }
    #pragma unroll
    for (int mask = 1; mask < 64; mask <<= 1) {
      pd += __shfl_xor(pd, mask);
      px += __shfl_xor(px, mask); py += __shfl_xor(py, mask);
      pz += __shfl_xor(pz, mask); pw += __shfl_xor(pw, mask);
    }
    if ((tid & 63) == 0) {
      int wv = tid >> 6;
      padr[wv][0] = pd; padr[wv][1] = px; padr[wv][2] = py;
      padr[wv][3] = pz; padr[wv][4] = pw;
    }
  }
  __syncthreads();
  if (tid < 64) {
    float dsum=0.f, ox=0.f, oy=0.f, oz=0.f, ow=0.f;
    #pragma unroll
    for (int ss = 0; ss < 8; ++ss) {
      dsum += red[ss][0][tid];
      ox += red[ss][1][tid]; oy += red[ss][2][tid];
      oz += red[ss][3][tid]; ow += red[ss][4][tid];
    }
    float inv = 1.f / dsum;
    int t = 512 + qb*64 + tid;
    int i = t >> 5, j = t & 31;
    float* ap = att + b*65536 + (i*4+u)*128 + (j*4+v);
    ap[0]     = ox*inv;
    ap[16384] = oy*inv;
    ap[32768] = oz*inv;
    ap[49152] = ow*inv;
  } else if (qb == 0 && tid == 64) {
    float dsum=0.f, ox=0.f, oy=0.f, oz=0.f, ow=0.f;
    #pragma unroll
    for (int wv = 0; wv < 8; ++wv) {
      dsum += padr[wv][0];
      ox += padr[wv][1]; oy += padr[wv][2]; oz += padr[wv][3]; ow += padr[wv][4];
    }
    float inv = 1.f / dsum;
    padout[0] = ox*inv; padout[1] = oy*inv; padout[2] = oz*inv; padout[3] = ow*inv;
  }
  __syncthreads();
  if (qb == 0) {
    int i = tid >> 5, j = tid & 31;
    float* ap = att + b*65536 + (i*4+u)*128 + (j*4+v);
    ap[0] = padout[0]; ap[16384] = padout[1];
    ap[32768] = padout[2]; ap[49152] = padout[3];
  }
}

// ================= K4: y = x + Wf@att + bias -> d_out; h1 = relu(wf1@y) ==============
// 1024 blocks x 256 threads: 8 pixel-quads x 32 groups. Folded weights from ws.
__global__ __launch_bounds__(256) void k4_y_h1(
    const float* __restrict__ x, const float* __restrict__ att,
    const float* __restrict__ wfold,
    const float* __restrict__ wf1, const float* __restrict__ bf1,
    float* __restrict__ yout, float* __restrict__ h1) {
  __shared__ float4 sWf4[64];
  __shared__ float sbfc[64];
  __shared__ float sw1t[1024];
  __shared__ float sb1[16];
  __shared__ float4 satt[4][8];
  __shared__ float4 ylds[64][8];
  int tid = threadIdx.x;
  if (tid < 64) sWf4[tid] = ((const float4*)wfold)[tid];
  else if (tid < 128) sbfc[tid-64] = wfold[256 + tid - 64];
  for (int i = tid; i < 1024; i += 256) {
    int c = i >> 4, o2 = i & 15;
    sw1t[i] = wf1[o2*64 + c];
  }
  if (tid < 16) sb1[tid] = bf1[tid];
  int quad = tid & 7, og = tid >> 3;
  int gq = blockIdx.x*8 + quad;
  int bb = gq >> 12, px0 = (gq & 4095)*4;
  if (tid < 32) {
    int k = tid >> 3, q2 = tid & 7;
    int gq2 = blockIdx.x*8 + q2;
    int b2i = gq2 >> 12, p0 = (gq2 & 4095)*4;
    satt[k][q2] = *(const float4*)(att + b2i*65536 + k*16384 + p0);
  }
  __syncthreads();
  float4 a0 = satt[0][quad], a1 = satt[1][quad], a2 = satt[2][quad], a3 = satt[3][quad];
  const float* xp = x + bb*CHW + px0;
  float* yp = yout + bb*CHW + px0;
  #pragma unroll
  for (int cc = 0; cc < 2; ++cc) {
    int c = og*2 + cc;
    float4 xv = *(const float4*)(xp + c*16384);
    float4 wf = sWf4[c];
    float bv = sbfc[c];
    float4 yv;
    yv.x = xv.x + wf.x*a0.x + wf.y*a1.x + wf.z*a2.x + wf.w*a3.x + bv;
    yv.y = xv.y + wf.x*a0.y + wf.y*a1.y + wf.z*a2.y + wf.w*a3.y + bv;
    yv.z = xv.z + wf.x*a0.z + wf.y*a1.z + wf.z*a2.z + wf.w*a3.z + bv;
    yv.w = xv.w + wf.x*a0.w + wf.y*a1.w + wf.z*a2.w + wf.w*a3.w + bv;
    *(float4*)(yp + c*16384) = yv;
    ylds[c][quad] = yv;
  }
  __syncthreads();
  if (og < 16) {
    float bv = sb1[og];
    float4 acc = make_float4(bv, bv, bv, bv);
    #pragma unroll 8
    for (int c = 0; c < 64; ++c) {
      float w = sw1t[c*16 + og];
      float4 yv = ylds[c][quad];
      acc.x += w*yv.x; acc.y += w*yv.y; acc.z += w*yv.z; acc.w += w*yv.w;
    }
    acc.x = fmaxf(acc.x,0.f); acc.y = fmaxf(acc.y,0.f);
    acc.z = fmaxf(acc.z,0.f); acc.w = fmaxf(acc.w,0.f);
    *(float4*)(h1 + bb*262144 + og*16384 + px0) = acc;
  }
}

// ================= K6: out = y + wf3@relu(dilconv(h1)+bf2) + bf3 =====================
// 1024 blocks x 256 threads: quarter-row tiles (32 px) x 8 o2-groups (2 h2-ch each).
__global__ __launch_bounds__(256) void k6_ff_out(
    const float* __restrict__ h1, const float* __restrict__ wf2,
    const float* __restrict__ bf2, const float* __restrict__ wf3,
    const float* __restrict__ bf3, float* yo) {
  __shared__ float sbuf[16][3][40];
  __shared__ float sW2t[2304];
  __shared__ float sw3[1024];
  __shared__ float sb2[16], sb3[64];
  __shared__ float sh2[32][17];
  int tid = threadIdx.x;
  int bi = blockIdx.x;
  int bb = bi >> 9, h = (bi >> 2) & 127, wq = bi & 3;
  int W0 = wq * 32;
  for (int idx = tid; idx < 1920; idx += 256) {
    int c = idx / 120;
    int rem = idx % 120;
    int r = rem / 40, cl = rem % 40;
    int row = h - 5 + 2*r;
    int gw = W0 - 4 + cl;
    float v = 0.f;
    if (row >= 0 && gw >= 0 && gw < 128)
      v = h1[bb*262144 + c*16384 + row*128 + gw];
    sbuf[c][r][cl] = v;
  }
  for (int i2 = tid; i2 < 2304; i2 += 256) {
    int o2 = i2 & 15, rest = i2 >> 4;
    int t = rest % 3, r = (rest/3) % 3, c = rest/9;
    sW2t[i2] = wf2[((o2*16 + c)*3 + r)*3 + t];
  }
  for (int i2 = tid; i2 < 1024; i2 += 256) sw3[i2] = wf3[i2];
  if (tid < 16) sb2[tid] = bf2[tid];
  else if (tid < 80) sb3[tid-16] = bf3[tid-16];
  __syncthreads();
  int w = tid & 31, og = tid >> 5;
  float acc0 = sb2[og*2], acc1 = sb2[og*2+1];
  #pragma unroll 4
  for (int c = 0; c < 16; ++c) {
    #pragma unroll
    for (int r = 0; r < 3; ++r) {
      float tm = sbuf[c][r][w+2];
      float t0 = sbuf[c][r][w+4];
      float tp = sbuf[c][r][w+6];
      int base = ((c*3 + r)*3) << 4;
      acc0 += sW2t[base + og*2]      * tm + sW2t[base + 16 + og*2]     * t0 + sW2t[base + 32 + og*2]     * tp;
      acc1 += sW2t[base + og*2 + 1]  * tm + sW2t[base + 16 + og*2 + 1] * t0 + sW2t[base + 32 + og*2 + 1] * tp;
    }
  }
  sh2[w][og*2]   = fmaxf(acc0, 0.f);
  sh2[w][og*2+1] = fmaxf(acc1, 0.f);
  __syncthreads();
  float hv[16];
  #pragma unroll
  for (int k = 0; k < 16; ++k) hv[k] = sh2[w][k];
  float* ybase = yo + bb*CHW + h*128 + W0 + w;
  #pragma unroll 2
  for (int oc = 0; oc < 8; ++oc) {
    int o = og*8 + oc;
    float sv = sb3[o] + ybase[o*16384];
    const float* s3 = &sw3[o*16];
    #pragma unroll
    for (int k = 0; k < 16; ++k) sv += s3[k]*hv[k];
    ybase[o*16384] = sv;
  }
}

extern "C" void kernel_launch(void* const* d_in, const int* in_sizes, int n_in,
                              void* d_out, int out_size, void* d_ws, size_t ws_size,
                              hipStream_t stream) {
  (void)in_sizes; (void)n_in; (void)out_size; (void)ws_size;
  const float* x   = (const float*)d_in[0];
  const float* w1a = (const float*)d_in[1];
  const float* b1a = (const float*)d_in[2];
  const float* w1b = (const float*)d_in[3];
  const float* b1b = (const float*)d_in[4];
  const float* wqk = (const float*)d_in[5];
  const float* w2  = (const float*)d_in[6];
  const float* b2  = (const float*)d_in[7];
  const float* wc  = (const float*)d_in[8];
  const float* bc  = (const float*)d_in[9];
  const float* wf1 = (const float*)d_in[10];
  const float* bf1 = (const float*)d_in[11];
  const float* wf2 = (const float*)d_in[12];
  const float* bf2 = (const float*)d_in[13];
  const float* wf3 = (const float*)d_in[14];
  const float* bf3 = (const float*)d_in[15];

  float* ws = (float*)d_ws;
  float* a_    = ws;               // 131072 floats
  float* stats = ws + 131072;      // 1024
  float* att   = ws + 132096;      // 131072
  float* h1    = ws + 263168;      // 524288
  float* wfold = ws + 787456;      // 320
  float* y     = (float*)d_out;    // y staged in d_out; k6 finalizes in place

  k1_a_stats<<<512,  256, 0, stream>>>(x, w1a, b1a, w1b, b1b, w2, b2, wc, bc,
                                       a_, stats, wfold);
  k23_attn  <<<256,  512, 0, stream>>>(a_, stats, wqk, att);
  k4_y_h1   <<<1024, 256, 0, stream>>>(x, att, wfold, wf1, bf1, y, h1);
  k6_ff_out <<<1024, 256, 0, stream>>>(h1, wf2, bf2, wf3, bf3, y);
}